// Round 2
// baseline (621.606 us; speedup 1.0000x reference)
//
#include <hip/hip_runtime.h>
#include <stdint.h>
#include <math.h>

// Problem constants (fixed by setup_inputs: B=4, N=4096, H=2048, L=64, K=8)
constexpr int H      = 2048;
constexpr int L      = 64;
constexpr int K_SEL  = 8;
constexpr int TM     = 64;          // rows per output tile
constexpr int BK     = 64;          // k-chunk per LDS stage
constexpr int KSPLIT = 4;           // K-split factor: grid 1024 -> 4 blocks/CU (fix round-1 latency bound)
constexpr int KB     = H / KSPLIT;  // 512 k per block
constexpr int SR     = 72;          // LDS row stride (floats): 72*4B=288B, 16B-aligned; staging writes floor-optimal
// EPS: fp32 logit rms error ~5e-7 (measured-model: eps*sqrt(sum E[s_k^2])); 2e-3 = ~4000 sigma.
// Rows whose min adjacent biased-gap over ranks 1..9 < EPS get exact fp64 recompute (~2-4% of rows).
constexpr float EPS_GAP = 2e-3f;

// ws layout (4-byte units). Total ~4.8 MB.
constexpr int WS_COUNTS = 0;        // uint[65]: per-expert counts + [64]=active rows
constexpr int WS_NFIX   = 128;      // uint: fixup-row count
constexpr int WS_LIST   = 256;      // uint[16384]: fixup row indices
constexpr int WS_WT     = 16640;    // float[2048*64]: W transposed (Wt[k][l]) for coalesced fixup reads
constexpr int WS_LOGITS = 147712;   // float[16384*64]: fp32 logits (atomic-accumulated partials)

// ---------------------------------------------------------------- prep ----
// blocks [0,1024): zero logits; [1024,1056): transpose W -> Wt; 1056: zero counters.
__global__ void prep(const float* __restrict__ Wr, float* __restrict__ wsf,
                     unsigned int* __restrict__ wsu)
{
    const int b = blockIdx.x, t = threadIdx.x;
    if (b < 1024) {
        float4* p = (float4*)(wsf + WS_LOGITS);           // 1024*256 float4 = 1M floats exactly
        p[b * 256 + t] = make_float4(0.f, 0.f, 0.f, 0.f);
    } else if (b < 1056) {
        const int b2 = b - 1024;                          // covers k = b2*64 .. +63
        float* Wt = wsf + WS_WT;
        #pragma unroll
        for (int i = 0; i < 16; ++i) {
            int w = b2 * 4096 + i * 256 + t;              // linear over k*64+l (coalesced writes)
            int k = w >> 6, l = w & 63;
            Wt[w] = Wr[(size_t)l * H + k];
        }
    } else {
        if (t < 66) wsu[WS_COUNTS + t] = 0u;
        if (t == 0) wsu[WS_NFIX] = 0u;
    }
}

// ---------------------------------------------------------------- gemm ----
// fp32 64x64 tile, 4x4 per-thread, K-split x4. LDS [r][k] stride-72: staging
// b128 writes spread <=8 words/bank (floor-optimal); reads are 16-way broadcasts.
__global__ __launch_bounds__(256, 4)
void gemm_partial(const float* __restrict__ x, const float* __restrict__ Wr,
                  float* __restrict__ logits)
{
    __shared__ __align__(16) float xs[TM * SR];
    __shared__ __align__(16) float wl[L * SR];

    const int t    = threadIdx.x;
    const int tile = blockIdx.x & 255;
    const int kb   = blockIdx.x >> 8;
    const int R0   = tile * TM;
    const int k0   = kb * KB;

    const int srow = t >> 4;            // staging row 0..15 (+16i)
    const int skq  = (t & 15) * 4;      // staging k offset 0..60
    const int r0   = (t >> 4) * 4;      // compute: 4 rows
    const int c0   = (t & 15) * 4;      // compute: 4 cols

    float acc[4][4] = {};
    float4 xg[4], wg[4];

    // register-prefetch stage 0
    #pragma unroll
    for (int i = 0; i < 4; ++i) {
        int row = srow + i * 16;
        xg[i] = *(const float4*)(x  + (size_t)(R0 + row) * H + k0 + skq);
        wg[i] = *(const float4*)(Wr + (size_t)row * H + k0 + skq);
    }

    for (int s = 0; s < KB / BK; ++s) {
        #pragma unroll
        for (int i = 0; i < 4; ++i) {
            int row = srow + i * 16;
            *(float4*)(xs + row * SR + skq) = xg[i];
            *(float4*)(wl + row * SR + skq) = wg[i];
        }
        __syncthreads();

        if (s + 1 < KB / BK) {
            int ks = k0 + (s + 1) * BK;
            #pragma unroll
            for (int i = 0; i < 4; ++i) {
                int row = srow + i * 16;
                xg[i] = *(const float4*)(x  + (size_t)(R0 + row) * H + ks + skq);
                wg[i] = *(const float4*)(Wr + (size_t)row * H + ks + skq);
            }
        }

        #pragma unroll 2
        for (int kk = 0; kk < BK; kk += 4) {
            float4 xa[4], wb[4];
            #pragma unroll
            for (int i = 0; i < 4; ++i) xa[i] = *(const float4*)(xs + (r0 + i) * SR + kk);
            #pragma unroll
            for (int j = 0; j < 4; ++j) wb[j] = *(const float4*)(wl + (c0 + j) * SR + kk);
            #pragma unroll
            for (int i = 0; i < 4; ++i)
                #pragma unroll
                for (int j = 0; j < 4; ++j) {
                    acc[i][j] = fmaf(xa[i].x, wb[j].x, acc[i][j]);
                    acc[i][j] = fmaf(xa[i].y, wb[j].y, acc[i][j]);
                    acc[i][j] = fmaf(xa[i].z, wb[j].z, acc[i][j]);
                    acc[i][j] = fmaf(xa[i].w, wb[j].w, acc[i][j]);
                }
        }
        __syncthreads();
    }

    // merge K-split partials (4 contenders per address; ~4.2M atomics total, few us)
    #pragma unroll
    for (int i = 0; i < 4; ++i)
        #pragma unroll
        for (int j = 0; j < 4; ++j)
            atomicAdd(&logits[(size_t)(R0 + r0 + i) * L + (c0 + j)], acc[i][j]);
}

// -------------------------------------------------------------- select ----
// top-9 scan per row on fp32 logits; rows with min adjacent biased-gap < EPS
// go to the fixup list, others are finalized here.
__global__ __launch_bounds__(256)
void select_rows(const float* __restrict__ logits, const float* __restrict__ bias,
                 const unsigned char* __restrict__ am,
                 float* __restrict__ out_sel, float* __restrict__ out_probs,
                 unsigned int* __restrict__ g_counts, unsigned int* __restrict__ nfix,
                 unsigned int* __restrict__ list)
{
    __shared__ float lg[TM][L + 1];   // +1: scan reads lg[t][l] conflict-free
    __shared__ float bs[L];
    __shared__ unsigned int cnt[L + 1];

    const int t  = threadIdx.x;
    const int R0 = blockIdx.x * TM;

    if (t < L) bs[t] = bias[t];
    if (t < L + 1) cnt[t] = 0;
    #pragma unroll
    for (int i = 0; i < 16; ++i) {
        int w = i * 256 + t;
        lg[w >> 6][w & 63] = logits[(size_t)R0 * L + w];
    }
    __syncthreads();

    if (t < TM) {
        const int grow = R0 + t;
        unsigned long long chosen = 0ull;
        int idx[K_SEL];
        float prev = 0.f, gmin = INFINITY;
        for (int kk = 0; kk < K_SEL + 1; ++kk) {   // 9 rounds: need gap rank8->rank9
            float best = -INFINITY; int bi = 0;
            for (int l = 0; l < L; ++l) {
                if ((chosen >> l) & 1ull) continue;
                float v = lg[t][l] + bs[l];        // strict '>' == jax top_k tie-break (lowest idx)
                if (v > best) { best = v; bi = l; }
            }
            if (kk > 0) gmin = fminf(gmin, prev - best);
            prev = best;
            if (kk < K_SEL) { chosen |= 1ull << bi; idx[kk] = bi; }
        }

        if (gmin < EPS_GAP) {
            unsigned int p = atomicAdd(nfix, 1u);
            list[p] = (unsigned int)grow;
        } else {
            float zv[K_SEL], mx = -INFINITY;
            #pragma unroll
            for (int kk = 0; kk < K_SEL; ++kk) { zv[kk] = lg[t][idx[kk]]; mx = fmaxf(mx, zv[kk]); }
            float e[K_SEL], ssum = 0.f;
            #pragma unroll
            for (int kk = 0; kk < K_SEL; ++kk) { e[kk] = expf(zv[kk] - mx); ssum += e[kk]; }
            #pragma unroll
            for (int kk = 0; kk < K_SEL; ++kk) {
                out_sel[(size_t)grow * K_SEL + kk]   = (float)idx[kk];
                out_probs[(size_t)grow * K_SEL + kk] = e[kk] / ssum;
            }
            if (am[grow]) {
                atomicAdd(&cnt[L], 1u);
                #pragma unroll
                for (int kk = 0; kk < K_SEL; ++kk) atomicAdd(&cnt[idx[kk]], 1u);
            }
        }
    }
    __syncthreads();
    if (t < L + 1 && cnt[t]) atomicAdd(&g_counts[t], cnt[t]);
}

// --------------------------------------------------------------- fixup ----
// wave-per-row exact fp64 recompute: lane = expert, Wt reads coalesced (256B/instr),
// x row broadcast. Shuffle-butterfly argmax x8 (tie-break lowest index).
__global__ __launch_bounds__(256)
void fixup(const float* __restrict__ x, const float* __restrict__ Wt,
           const float* __restrict__ bias, const unsigned char* __restrict__ am,
           const unsigned int* __restrict__ nfix, const unsigned int* __restrict__ list,
           float* __restrict__ out_sel, float* __restrict__ out_probs,
           unsigned int* __restrict__ g_counts)
{
    const int lane = threadIdx.x & 63;
    const int wid  = (blockIdx.x << 2) | (threadIdx.x >> 6);
    const int nw   = gridDim.x << 2;
    const int n    = (int)*nfix;
    const double bl = (double)bias[lane];

    for (int i = wid; i < n; i += nw) {
        const int row = (int)list[i];
        const float* xr = x + (size_t)row * H;
        double acc = 0.0;
        #pragma unroll 4
        for (int k = 0; k < H; k += 4) {
            float4 xv = *(const float4*)(xr + k);          // wave-uniform broadcast
            float w0 = Wt[(k + 0) * L + lane];             // coalesced across lanes
            float w1 = Wt[(k + 1) * L + lane];
            float w2 = Wt[(k + 2) * L + lane];
            float w3 = Wt[(k + 3) * L + lane];
            acc = fma((double)xv.x, (double)w0, acc);
            acc = fma((double)xv.y, (double)w1, acc);
            acc = fma((double)xv.z, (double)w2, acc);
            acc = fma((double)xv.w, (double)w3, acc);
        }

        double v = acc + bl;                               // biased selection value
        int    widx[K_SEL];
        double wlog[K_SEL];
        #pragma unroll
        for (int kk = 0; kk < K_SEL; ++kk) {
            double mv = v; int mi = lane;
            #pragma unroll
            for (int off = 32; off; off >>= 1) {
                double ov = __shfl_xor(mv, off);
                int    oi = __shfl_xor(mi, off);
                if (ov > mv || (ov == mv && oi < mi)) { mv = ov; mi = oi; }
            }
            widx[kk] = mi;                                 // uniform across lanes
            wlog[kk] = __shfl(acc, mi);                    // winner's unbiased logit
            if (lane == mi) v = -INFINITY;
        }

        double mx = -INFINITY;
        #pragma unroll
        for (int kk = 0; kk < K_SEL; ++kk) mx = fmax(mx, wlog[kk]);
        float e[K_SEL], ssum = 0.f;
        #pragma unroll
        for (int kk = 0; kk < K_SEL; ++kk) { e[kk] = expf((float)(wlog[kk] - mx)); ssum += e[kk]; }

        if (lane < K_SEL) {
            out_sel[(size_t)row * K_SEL + lane]   = (float)widx[lane];
            out_probs[(size_t)row * K_SEL + lane] = e[lane] / ssum;
        }
        if (am[row]) {
            if (lane < K_SEL)  atomicAdd(&g_counts[widx[lane]], 1u);
            if (lane == K_SEL) atomicAdd(&g_counts[L], 1u);
        }
    }
}

// ------------------------------------------------------------ finalize ----
__global__ void router_finalize(const unsigned int* __restrict__ g_counts,
                                float* __restrict__ out_scalars)
{
    const int l = threadIdx.x;  // 64 threads, one wave
    const float denom = (float)g_counts[L] * (float)K_SEL;
    const float f = (float)g_counts[l] / denom;
    float d  = f - 1.0f / (float)L;
    float sq = d * d;
    #pragma unroll
    for (int o = 32; o > 0; o >>= 1) {
        sq += __shfl_down(sq, o);
        d = fmaxf(d, __shfl_down(d, o));
    }
    if (l == 0) {
        out_scalars[0] = (float)L * sq;  // load_balance_loss
        out_scalars[1] = (float)L * d;   // max_vio
    }
}

extern "C" void kernel_launch(void* const* d_in, const int* in_sizes, int n_in,
                              void* d_out, int out_size, void* d_ws, size_t ws_size,
                              hipStream_t stream)
{
    const float* x          = (const float*)d_in[0];
    const float* Wr         = (const float*)d_in[1];
    const float* bias       = (const float*)d_in[2];
    const unsigned char* am = (const unsigned char*)d_in[3];
    float* out = (float*)d_out;
    float* wsf = (float*)d_ws;
    unsigned int* wsu = (unsigned int*)d_ws;

    const int rows = in_sizes[3];  // B*N = 16384

    float* out_sel   = out;
    float* out_probs = out + (size_t)rows * K_SEL;
    float* out_scal  = out + (size_t)rows * K_SEL * 2;

    hipLaunchKernelGGL(prep,            dim3(1057),              dim3(256), 0, stream, Wr, wsf, wsu);
    hipLaunchKernelGGL(gemm_partial,    dim3(rows / TM * KSPLIT), dim3(256), 0, stream,
                       x, Wr, wsf + WS_LOGITS);
    hipLaunchKernelGGL(select_rows,     dim3(rows / TM),          dim3(256), 0, stream,
                       wsf + WS_LOGITS, bias, am, out_sel, out_probs,
                       wsu + WS_COUNTS, wsu + WS_NFIX, wsu + WS_LIST);
    hipLaunchKernelGGL(fixup,           dim3(128),               dim3(256), 0, stream,
                       x, wsf + WS_WT, bias, am, wsu + WS_NFIX, wsu + WS_LIST,
                       out_sel, out_probs, wsu + WS_COUNTS);
    hipLaunchKernelGGL(router_finalize, dim3(1),                 dim3(64),  0, stream,
                       wsu + WS_COUNTS, out_scal);
}

// Round 3
// 344.363 us; speedup vs baseline: 1.8051x; 1.8051x over previous
//
#include <hip/hip_runtime.h>
#include <stdint.h>
#include <math.h>

// Problem constants (fixed by setup_inputs: B=4, N=4096, H=2048, L=64, K=8)
constexpr int H     = 2048;
constexpr int L     = 64;
constexpr int K_SEL = 8;
constexpr int TM    = 32;    // rows per block -> grid 512 = 4 blocks/CU (8 waves/CU)
constexpr int BK    = 64;    // k-chunk per LDS stage
constexpr int SX    = 36;    // xs[k][r] stride: read quads (9k+ty)%8 -> conflict-free
constexpr int SW    = 68;    // ws[k][c] stride: read quads (17k+tx)%8 -> 2-way (free)
// EPS: fp32 accumulation noise-diff sigma ~3e-6; 1e-4 = 33 sigma. Rows whose min
// adjacent biased-gap over ranks 1..9 < EPS get exact fp64 recompute.
// n_fix ~ 16384*8*EPS/0.071 ~ 185 rows (r2 lesson: EPS=2e-3 gave ~3300 rows).
constexpr float EPS_GAP = 1e-4f;

// ws layout (4-byte units)
constexpr int WS_COUNTS = 0;        // uint[65]: per-expert counts + [64]=active rows
constexpr int WS_NFIX   = 128;      // uint: fixup-row count
constexpr int WS_LIST   = 256;      // uint[16384]: fixup row indices
constexpr int WS_WT     = 16640;    // float[2048*64]: W transposed (Wt[k][l]) for coalesced fixup

// ---------------------------------------------------------------- prep ----
// blocks [0,32): transpose W -> Wt via LDS tile (2-way banks both sides);
// block 32: zero counters.
__global__ __launch_bounds__(256)
void prep(const float* __restrict__ Wr, float* __restrict__ Wt,
          unsigned int* __restrict__ wsu)
{
    const int t = threadIdx.x, b = blockIdx.x;
    if (b == 32) {
        if (t < L + 1) wsu[WS_COUNTS + t] = 0u;
        if (t == 0)    wsu[WS_NFIX] = 0u;
        return;
    }
    __shared__ float tile[64 * 65];
    const int k0 = b * 64;
    {
        const int l = t >> 2, kq = (t & 3) * 16;
        #pragma unroll
        for (int j = 0; j < 4; ++j) {
            float4 v = *(const float4*)(Wr + (size_t)l * H + k0 + kq + 4 * j);
            int k = kq + 4 * j;
            tile[(k + 0) * 65 + l] = v.x;
            tile[(k + 1) * 65 + l] = v.y;
            tile[(k + 2) * 65 + l] = v.z;
            tile[(k + 3) * 65 + l] = v.w;
        }
    }
    __syncthreads();
    {
        const int k = t >> 2, lq = (t & 3) * 16;
        #pragma unroll
        for (int j = 0; j < 4; ++j) {
            int l2 = lq + 4 * j;
            float4 o = make_float4(tile[k * 65 + l2], tile[k * 65 + l2 + 1],
                                   tile[k * 65 + l2 + 2], tile[k * 65 + l2 + 3]);
            *(float4*)(Wt + (size_t)(k0 + k) * L + l2) = o;
        }
    }
}

// ---------------------------------------------------------------- main ----
// Fused fp32 GEMM (32x64 tile, full H, 4x4 thread tiles) + per-row top-9
// selection + gap-gated fixup list + per-block count histogram.
__global__ __launch_bounds__(128, 2)
void router_main(const float* __restrict__ x, const float* __restrict__ Wr,
                 const float* __restrict__ bias, const unsigned char* __restrict__ am,
                 float* __restrict__ out_sel, float* __restrict__ out_probs,
                 unsigned int* __restrict__ g_counts, unsigned int* __restrict__ nfix,
                 unsigned int* __restrict__ list)
{
    __shared__ __align__(16) float xs[BK * SX];     // [k][r]
    __shared__ __align__(16) float wls[BK * SW];    // [k][c]
    __shared__ float lg[TM][L + 1];
    __shared__ float bs[L];
    __shared__ unsigned int cnt[L + 1];

    const int t  = threadIdx.x;
    const int R0 = blockIdx.x * TM;
    const int r0 = 4 * (t >> 4);     // 8 row-groups
    const int c0 = 4 * (t & 15);     // 16 col-groups
    const int srow = t >> 2;         // staging row / w-col 0..31
    const int skq  = 4 * (t & 3);    // staging k base

    if (t < L) bs[t] = bias[t];
    if (t < L + 1) cnt[t] = 0;

    float acc[4][4] = {};
    float4 xg[4], wg[8];

    const float* xp  = x  + (size_t)(R0 + srow) * H + skq;
    const float* wp0 = Wr + (size_t)srow * H + skq;
    const float* wp1 = Wr + (size_t)(srow + 32) * H + skq;

    // prefetch stage 0
    #pragma unroll
    for (int i = 0; i < 4; ++i) {
        xg[i]     = *(const float4*)(xp  + 16 * i);
        wg[i]     = *(const float4*)(wp0 + 16 * i);
        wg[4 + i] = *(const float4*)(wp1 + 16 * i);
    }

    for (int s = 0; s < H / BK; ++s) {
        // stage into LDS (scalar writes: banks 16(tx&1)+4e+(t>>2) -> 2-way, free)
        #pragma unroll
        for (int i = 0; i < 4; ++i) {
            int k = skq + 16 * i;
            xs[(k + 0) * SX + srow] = xg[i].x;
            xs[(k + 1) * SX + srow] = xg[i].y;
            xs[(k + 2) * SX + srow] = xg[i].z;
            xs[(k + 3) * SX + srow] = xg[i].w;
            wls[(k + 0) * SW + srow] = wg[i].x;
            wls[(k + 1) * SW + srow] = wg[i].y;
            wls[(k + 2) * SW + srow] = wg[i].z;
            wls[(k + 3) * SW + srow] = wg[i].w;
            wls[(k + 0) * SW + srow + 32] = wg[4 + i].x;
            wls[(k + 1) * SW + srow + 32] = wg[4 + i].y;
            wls[(k + 2) * SW + srow + 32] = wg[4 + i].z;
            wls[(k + 3) * SW + srow + 32] = wg[4 + i].w;
        }
        __syncthreads();

        // prefetch next stage (hidden under the fma loop)
        if (s + 1 < H / BK) {
            int kb = (s + 1) * BK;
            #pragma unroll
            for (int i = 0; i < 4; ++i) {
                xg[i]     = *(const float4*)(xp  + kb + 16 * i);
                wg[i]     = *(const float4*)(wp0 + kb + 16 * i);
                wg[4 + i] = *(const float4*)(wp1 + kb + 16 * i);
            }
        }

        #pragma unroll 8
        for (int kk = 0; kk < BK; ++kk) {
            float4 xv = *(const float4*)(xs  + kk * SX + r0);   // 4 rows at k (bcast, conflict-free)
            float4 wv = *(const float4*)(wls + kk * SW + c0);   // 4 cols at k (2-way, free)
            acc[0][0] = fmaf(xv.x, wv.x, acc[0][0]);
            acc[0][1] = fmaf(xv.x, wv.y, acc[0][1]);
            acc[0][2] = fmaf(xv.x, wv.z, acc[0][2]);
            acc[0][3] = fmaf(xv.x, wv.w, acc[0][3]);
            acc[1][0] = fmaf(xv.y, wv.x, acc[1][0]);
            acc[1][1] = fmaf(xv.y, wv.y, acc[1][1]);
            acc[1][2] = fmaf(xv.y, wv.z, acc[1][2]);
            acc[1][3] = fmaf(xv.y, wv.w, acc[1][3]);
            acc[2][0] = fmaf(xv.z, wv.x, acc[2][0]);
            acc[2][1] = fmaf(xv.z, wv.y, acc[2][1]);
            acc[2][2] = fmaf(xv.z, wv.z, acc[2][2]);
            acc[2][3] = fmaf(xv.z, wv.w, acc[2][3]);
            acc[3][0] = fmaf(xv.w, wv.x, acc[3][0]);
            acc[3][1] = fmaf(xv.w, wv.y, acc[3][1]);
            acc[3][2] = fmaf(xv.w, wv.z, acc[3][2]);
            acc[3][3] = fmaf(xv.w, wv.w, acc[3][3]);
        }
        __syncthreads();
    }

    // park logits in LDS for per-row epilogue
    #pragma unroll
    for (int i = 0; i < 4; ++i)
        #pragma unroll
        for (int j = 0; j < 4; ++j)
            lg[r0 + i][c0 + j] = acc[i][j];
    __syncthreads();

    if (t < TM) {
        const int grow = R0 + t;
        unsigned long long chosen = 0ull;
        int idx[K_SEL];
        float prev = 0.f, gmin = INFINITY;
        for (int kk = 0; kk < K_SEL + 1; ++kk) {   // 9 rounds: need gap rank8->rank9
            float best = -INFINITY; int bi = 0;
            for (int l = 0; l < L; ++l) {
                if ((chosen >> l) & 1ull) continue;
                float v = lg[t][l] + bs[l];        // strict '>' == jax top_k tie-break
                if (v > best) { best = v; bi = l; }
            }
            if (kk > 0) gmin = fminf(gmin, prev - best);
            prev = best;
            if (kk < K_SEL) { chosen |= 1ull << bi; idx[kk] = bi; }
        }

        if (gmin < EPS_GAP) {
            unsigned int p = atomicAdd(nfix, 1u);
            list[p] = (unsigned int)grow;
        } else {
            float zv[K_SEL], mx = -INFINITY;
            #pragma unroll
            for (int kk = 0; kk < K_SEL; ++kk) { zv[kk] = lg[t][idx[kk]]; mx = fmaxf(mx, zv[kk]); }
            float e[K_SEL], ssum = 0.f;
            #pragma unroll
            for (int kk = 0; kk < K_SEL; ++kk) { e[kk] = expf(zv[kk] - mx); ssum += e[kk]; }
            #pragma unroll
            for (int kk = 0; kk < K_SEL; ++kk) {
                out_sel[(size_t)grow * K_SEL + kk]   = (float)idx[kk];
                out_probs[(size_t)grow * K_SEL + kk] = e[kk] / ssum;
            }
            if (am[grow]) {
                atomicAdd(&cnt[L], 1u);
                #pragma unroll
                for (int kk = 0; kk < K_SEL; ++kk) atomicAdd(&cnt[idx[kk]], 1u);
            }
        }
    }
    __syncthreads();
    if (t < L + 1 && cnt[t]) atomicAdd(&g_counts[t], cnt[t]);
}

// --------------------------------------------------------------- fixup ----
// wave-per-row exact fp64 recompute; 1024 waves >> n_fix (~200) -> <=1 row/wave.
// 4 independent accumulators break the dfma dependency chain (r2 lesson).
__global__ __launch_bounds__(256)
void fixup(const float* __restrict__ x, const float* __restrict__ Wt,
           const float* __restrict__ bias, const unsigned char* __restrict__ am,
           const unsigned int* __restrict__ nfix, const unsigned int* __restrict__ list,
           float* __restrict__ out_sel, float* __restrict__ out_probs,
           unsigned int* __restrict__ g_counts)
{
    const int lane = threadIdx.x & 63;
    const int wid  = (blockIdx.x << 2) | (threadIdx.x >> 6);
    const int nw   = gridDim.x << 2;
    const int n    = (int)*nfix;
    const double bl = (double)bias[lane];

    for (int i = wid; i < n; i += nw) {
        const int row = (int)list[i];
        const float* xr = x + (size_t)row * H;
        double a0 = 0.0, a1 = 0.0, a2 = 0.0, a3 = 0.0;
        #pragma unroll 2
        for (int k = 0; k < H; k += 16) {
            float4 x0 = *(const float4*)(xr + k);
            float4 x1 = *(const float4*)(xr + k + 4);
            float4 x2 = *(const float4*)(xr + k + 8);
            float4 x3 = *(const float4*)(xr + k + 12);
            a0 = fma((double)x0.x, (double)Wt[(k +  0) * L + lane], a0);
            a1 = fma((double)x0.y, (double)Wt[(k +  1) * L + lane], a1);
            a2 = fma((double)x0.z, (double)Wt[(k +  2) * L + lane], a2);
            a3 = fma((double)x0.w, (double)Wt[(k +  3) * L + lane], a3);
            a0 = fma((double)x1.x, (double)Wt[(k +  4) * L + lane], a0);
            a1 = fma((double)x1.y, (double)Wt[(k +  5) * L + lane], a1);
            a2 = fma((double)x1.z, (double)Wt[(k +  6) * L + lane], a2);
            a3 = fma((double)x1.w, (double)Wt[(k +  7) * L + lane], a3);
            a0 = fma((double)x2.x, (double)Wt[(k +  8) * L + lane], a0);
            a1 = fma((double)x2.y, (double)Wt[(k +  9) * L + lane], a1);
            a2 = fma((double)x2.z, (double)Wt[(k + 10) * L + lane], a2);
            a3 = fma((double)x2.w, (double)Wt[(k + 11) * L + lane], a3);
            a0 = fma((double)x3.x, (double)Wt[(k + 12) * L + lane], a0);
            a1 = fma((double)x3.y, (double)Wt[(k + 13) * L + lane], a1);
            a2 = fma((double)x3.z, (double)Wt[(k + 14) * L + lane], a2);
            a3 = fma((double)x3.w, (double)Wt[(k + 15) * L + lane], a3);
        }
        double acc = (a0 + a1) + (a2 + a3);

        double v = acc + bl;
        int    widx[K_SEL];
        double wlog[K_SEL];
        #pragma unroll
        for (int kk = 0; kk < K_SEL; ++kk) {
            double mv = v; int mi = lane;
            #pragma unroll
            for (int off = 32; off; off >>= 1) {
                double ov = __shfl_xor(mv, off);
                int    oi = __shfl_xor(mi, off);
                if (ov > mv || (ov == mv && oi < mi)) { mv = ov; mi = oi; }
            }
            widx[kk] = mi;
            wlog[kk] = __shfl(acc, mi);
            if (lane == mi) v = -INFINITY;
        }

        double mx = -INFINITY;
        #pragma unroll
        for (int kk = 0; kk < K_SEL; ++kk) mx = fmax(mx, wlog[kk]);
        float e[K_SEL], ssum = 0.f;
        #pragma unroll
        for (int kk = 0; kk < K_SEL; ++kk) { e[kk] = expf((float)(wlog[kk] - mx)); ssum += e[kk]; }

        if (lane < K_SEL) {
            out_sel[(size_t)row * K_SEL + lane]   = (float)widx[lane];
            out_probs[(size_t)row * K_SEL + lane] = e[lane] / ssum;
        }
        if (am[row]) {
            if (lane < K_SEL)  atomicAdd(&g_counts[widx[lane]], 1u);
            if (lane == K_SEL) atomicAdd(&g_counts[L], 1u);
        }
    }
}

// ------------------------------------------------------------ finalize ----
__global__ void router_finalize(const unsigned int* __restrict__ g_counts,
                                float* __restrict__ out_scalars)
{
    const int l = threadIdx.x;  // one wave
    const float denom = (float)g_counts[L] * (float)K_SEL;
    const float f = (float)g_counts[l] / denom;
    float d  = f - 1.0f / (float)L;
    float sq = d * d;
    #pragma unroll
    for (int o = 32; o > 0; o >>= 1) {
        sq += __shfl_down(sq, o);
        d = fmaxf(d, __shfl_down(d, o));
    }
    if (l == 0) {
        out_scalars[0] = (float)L * sq;  // load_balance_loss
        out_scalars[1] = (float)L * d;   // max_vio
    }
}

extern "C" void kernel_launch(void* const* d_in, const int* in_sizes, int n_in,
                              void* d_out, int out_size, void* d_ws, size_t ws_size,
                              hipStream_t stream)
{
    const float* x          = (const float*)d_in[0];
    const float* Wr         = (const float*)d_in[1];
    const float* bias       = (const float*)d_in[2];
    const unsigned char* am = (const unsigned char*)d_in[3];
    float* out = (float*)d_out;
    float* wsf = (float*)d_ws;
    unsigned int* wsu = (unsigned int*)d_ws;

    const int rows = in_sizes[3];  // B*N = 16384

    float* out_sel   = out;
    float* out_probs = out + (size_t)rows * K_SEL;
    float* out_scal  = out + (size_t)rows * K_SEL * 2;

    hipLaunchKernelGGL(prep,            dim3(33),        dim3(256), 0, stream,
                       Wr, wsf + WS_WT, wsu);
    hipLaunchKernelGGL(router_main,     dim3(rows / TM), dim3(128), 0, stream,
                       x, Wr, bias, am, out_sel, out_probs,
                       wsu + WS_COUNTS, wsu + WS_NFIX, wsu + WS_LIST);
    hipLaunchKernelGGL(fixup,           dim3(256),       dim3(256), 0, stream,
                       x, wsf + WS_WT, bias, am, wsu + WS_NFIX, wsu + WS_LIST,
                       out_sel, out_probs, wsu + WS_COUNTS);
    hipLaunchKernelGGL(router_finalize, dim3(1),         dim3(64),  0, stream,
                       wsu + WS_COUNTS, out_scal);
}